// Round 1
// baseline (126.213 us; speedup 1.0000x reference)
//
#include <hip/hip_runtime.h>

#define NUM_CODES 512
#define DIM 64
#define NPIX (32 * 64 * 64)  // 131072 pixels
#define CT (NUM_CODES / 16)  // 32 code tiles of 16 codes
#define BLK 256
#define NGRP 2               // pixel groups per wave (16 px each) -> 32 px/wave
#define PPB 128              // pixels per block = 4 waves * 32 px

typedef __attribute__((ext_vector_type(8))) short bf16x8;
typedef __attribute__((ext_vector_type(4))) float f32x4;

__device__ __forceinline__ unsigned short f2bf(float f) {
    unsigned u = __float_as_uint(f);
    return (unsigned short)((u + 0x7fffu + ((u >> 16) & 1u)) >> 16);
}
__device__ __forceinline__ float bf2f(unsigned short h) {
    return __uint_as_float(((unsigned)h) << 16);
}

// ---------------------------------------------------------------------------
// Prep: swizzle NEGATED codebook into bf16 hi/lo A-fragment order + exact
// l2e + l2e/2. A-frag (16x16x32): lane = (k_in_32/8)*16 + m, elem j = k%8.
// With -e in A and acc initialized to l2e/2, the MFMA output IS the
// selection key  l2e/2 - dot  directly.
// ---------------------------------------------------------------------------
__global__ __launch_bounds__(256) void prep_kernel(
    const float* __restrict__ emb, unsigned short* __restrict__ AH,
    unsigned short* __restrict__ ALO, float* __restrict__ l2e,
    float* __restrict__ l2eh) {
    const int t = blockIdx.x * 256 + threadIdx.x;  // 0..8191
    const int e0 = t * 4;
    const int c = e0 >> 6, d0 = e0 & 63;
    const float4 v = *(const float4*)(emb + c * DIM + d0);
    float f[4] = {-v.x, -v.y, -v.z, -v.w};  // NEGATED
    unsigned short h[4], l[4];
#pragma unroll
    for (int i = 0; i < 4; ++i) {
        h[i] = f2bf(f[i]);
        l[i] = f2bf(f[i] - bf2f(h[i]));
    }
    const int ct = c >> 4, mr = c & 15, s = d0 >> 5, q = (d0 & 31) >> 3,
              j0 = d0 & 7;
    const int base = ((ct * 2 + s) * 64 + (q * 16 + mr)) * 8 + j0;
    *(ushort4*)(AH + base) = make_ushort4(h[0], h[1], h[2], h[3]);
    *(ushort4*)(ALO + base) = make_ushort4(l[0], l[1], l[2], l[3]);

    if (t < NUM_CODES) {  // exact ||e||^2, validated pairwise-8 order
        const float* e = emb + t * DIM;
        float r[8];
#pragma unroll
        for (int j = 0; j < 8; ++j) {
            float w = e[j];
            r[j] = w * w;
        }
#pragma unroll
        for (int i = 8; i < DIM; i += 8)
#pragma unroll
            for (int j = 0; j < 8; ++j) {
                float w = e[i + j];
                r[j] += w * w;
            }
        float sv =
            ((r[0] + r[1]) + (r[2] + r[3])) + ((r[4] + r[5]) + (r[6] + r[7]));
        l2e[t] = sv;
        l2eh[t] = 0.5f * sv;
    }
}

// ---------------------------------------------------------------------------
// Main: 4 waves / 128 px. NGRP=2 (32 px/wave) doubles the grid to 1024
// blocks -> 4 blocks/CU -> 4 waves/SIMD (was 2): latency hiding via TLP.
// Per tile: acc initialized with l2e/2 (single ds_read_b128), 6 MFMAs with
// negated codebook give the key directly; next tile's A-frags prefetched
// into registers. Top-2 insert (med3-optimized, identical semantics) /
// cross-lane merge / exact refine identical to validated logic.
// ---------------------------------------------------------------------------
__global__ __launch_bounds__(BLK, 4) void vq_main(
    const float* __restrict__ x_in, const unsigned short* __restrict__ AH,
    const unsigned short* __restrict__ ALO, const float* __restrict__ l2e,
    const float* __restrict__ l2eh, const float* __restrict__ emb,
    float* __restrict__ codes_out, float* __restrict__ vecs_out) {
    __shared__ float s_l2eh[NUM_CODES];
    __shared__ float s_l2ex[NUM_CODES];
    __shared__ int s_top[PPB][2];
    __shared__ int s_code[PPB];

    const int tid = threadIdx.x, lane = tid & 63, wave = tid >> 6;
    s_l2eh[tid] = l2eh[tid];
    s_l2eh[tid + 256] = l2eh[tid + 256];
    s_l2ex[tid] = l2e[tid];
    s_l2ex[tid + 256] = l2e[tid + 256];
    __syncthreads();

    const int p = lane & 15, q = lane >> 4;
    const int pw = blockIdx.x * PPB + wave * (16 * NGRP);  // wave's 32 px

    // ---- B fragments for NGRP groups: B[k][n]: n=lane&15, k=(lane>>4)*8+j --
    bf16x8 bh0[NGRP], bl0[NGRP], bh1[NGRP], bl1[NGRP];
#pragma unroll
    for (int g = 0; g < NGRP; ++g) {
        const float* xb = x_in + (size_t)(pw + g * 16 + p) * DIM + q * 8;
        float4 u0 = *(const float4*)(xb);
        float4 u1 = *(const float4*)(xb + 4);
        float4 u2 = *(const float4*)(xb + 32);
        float4 u3 = *(const float4*)(xb + 36);
        float f0[8] = {u0.x, u0.y, u0.z, u0.w, u1.x, u1.y, u1.z, u1.w};
        float f1[8] = {u2.x, u2.y, u2.z, u2.w, u3.x, u3.y, u3.z, u3.w};
#pragma unroll
        for (int j = 0; j < 8; ++j) {
            unsigned short hh = f2bf(f0[j]);
            bh0[g][j] = (short)hh;
            bl0[g][j] = (short)f2bf(f0[j] - bf2f(hh));
            unsigned short h2 = f2bf(f1[j]);
            bh1[g][j] = (short)h2;
            bl1[g][j] = (short)f2bf(f1[j] - bf2f(h2));
        }
    }

    const int rowbase = q * 4;  // C/D: row = (lane>>4)*4 + reg
    float d1[NGRP], d2[NGRP];
    int k1[NGRP], k2[NGRP];
#pragma unroll
    for (int g = 0; g < NGRP; ++g) {
        d1[g] = 3.4e38f;
        d2[g] = 3.4e38f;
        k1[g] = 0;
        k2[g] = 0;
    }

    const unsigned short* pAH = AH + lane * 8;
    const unsigned short* pAL = ALO + lane * 8;

    // ---- prime tile 0's A-fragments ----
    bf16x8 a0h = *(const bf16x8*)(pAH);
    bf16x8 a0l = *(const bf16x8*)(pAL);
    bf16x8 a1h = *(const bf16x8*)(pAH + 512);
    bf16x8 a1l = *(const bf16x8*)(pAL + 512);

    for (int ct = 0; ct < CT; ++ct) {
        // prefetch next tile (wraps to 0 on last iter; harmless)
        const int nt = (ct + 1) & (CT - 1);
        const bf16x8 n0h = *(const bf16x8*)(pAH + nt * 1024);
        const bf16x8 n0l = *(const bf16x8*)(pAL + nt * 1024);
        const bf16x8 n1h = *(const bf16x8*)(pAH + nt * 1024 + 512);
        const bf16x8 n1l = *(const bf16x8*)(pAL + nt * 1024 + 512);

        const int kb = ct * 16 + rowbase;
        // acc-init with l2e/2: one ds_read_b128 (kb is 16B-aligned)
        const f32x4 acc_init = *(const f32x4*)&s_l2eh[kb];

#pragma unroll
        for (int g = 0; g < NGRP; ++g) {
            f32x4 acc = acc_init;
            acc = __builtin_amdgcn_mfma_f32_16x16x32_bf16(a0h, bh0[g], acc, 0, 0, 0);
            acc = __builtin_amdgcn_mfma_f32_16x16x32_bf16(a1h, bh1[g], acc, 0, 0, 0);
            acc = __builtin_amdgcn_mfma_f32_16x16x32_bf16(a0l, bh0[g], acc, 0, 0, 0);
            acc = __builtin_amdgcn_mfma_f32_16x16x32_bf16(a1l, bh1[g], acc, 0, 0, 0);
            acc = __builtin_amdgcn_mfma_f32_16x16x32_bf16(a0h, bl0[g], acc, 0, 0, 0);
            acc = __builtin_amdgcn_mfma_f32_16x16x32_bf16(a1h, bl1[g], acc, 0, 0, 0);

#pragma unroll
            for (int r = 0; r < 4; ++r) {
                const float d = acc[r];  // = l2e/2 - dot  (key, no sub)
                const int kk = kb + r;
                const bool c = d < d1[g], c2 = d < d2[g];
                // med3(d1,d2,d) == (c ? d1 : (c2 ? d : d2)) given d1<=d2;
                // k-selects keep the exact validated strict-'<' tie rules.
                const float nd2 = __builtin_amdgcn_fmed3f(d1[g], d2[g], d);
                const int nk2 = c2 ? kk : k2[g];
                k2[g] = c ? k1[g] : nk2;
                k1[g] = c ? kk : k1[g];
                d2[g] = nd2;
                d1[g] = fminf(d1[g], d);
            }
        }
        a0h = n0h;
        a0l = n0l;
        a1h = n1h;
        a1l = n1l;
    }

    // ---- cross-lane top-2 merge (lanes l, l^16, l^32 share pixel col) ----
#pragma unroll
    for (int g = 0; g < NGRP; ++g) {
        float a1 = d1[g], a2 = d2[g];
        int b1 = k1[g], b2 = k2[g];
#pragma unroll
        for (int off = 16; off <= 32; off <<= 1) {
            const float od1 = __shfl_xor(a1, off);
            const int ok1 = __shfl_xor(b1, off);
            const float od2 = __shfl_xor(a2, off);
            const int ok2 = __shfl_xor(b2, off);
            const bool c = od1 < a1;
            const float w1 = c ? od1 : a1;
            const int wk1 = c ? ok1 : b1;
            const float l1 = c ? a1 : od1;
            const int lk1 = c ? b1 : ok1;
            const bool cm = od2 < a2;
            const float m2 = cm ? od2 : a2;
            const int mk2 = cm ? ok2 : b2;
            const bool c3 = m2 < l1;
            a2 = c3 ? m2 : l1;
            b2 = c3 ? mk2 : lk1;
            a1 = w1;
            b1 = wk1;
        }
        if (lane < 16) {
            const int pb = wave * (16 * NGRP) + g * 16 + lane;
            s_top[pb][0] = b1;
            s_top[pb][1] = b2;
        }
    }
    __syncthreads();

    // ---- exact refine of the 2 candidates (validated arithmetic),
    //      one pixel per thread, tid < PPB active ----
    if (tid < PPB) {
        const int pix = blockIdx.x * PPB + tid;
        int ka = s_top[tid][0], kb2 = s_top[tid][1];
        if (kb2 < ka) {
            const int tt = ka;
            ka = kb2;
            kb2 = tt;
        }
        const float* xr = x_in + (size_t)pix * DIM;
        float x[DIM];
#pragma unroll
        for (int jj = 0; jj < 16; ++jj) {
            const float4 v = *(const float4*)(xr + jj * 4);
            x[4 * jj + 0] = v.x;
            x[4 * jj + 1] = v.y;
            x[4 * jj + 2] = v.z;
            x[4 * jj + 3] = v.w;
        }
        float r[8];
#pragma unroll
        for (int j = 0; j < 8; ++j) r[j] = x[j] * x[j];
#pragma unroll
        for (int i = 8; i < DIM; i += 8)
#pragma unroll
            for (int j = 0; j < 8; ++j) r[j] += x[i + j] * x[i + j];
        const float l2x =
            ((r[0] + r[1]) + (r[2] + r[3])) + ((r[4] + r[5]) + (r[6] + r[7]));

        const float* ea = emb + (size_t)ka * DIM;
        float acca = 0.f;
#pragma unroll
        for (int d = 0; d < DIM; ++d) acca = __builtin_fmaf(x[d], ea[d], acca);
        const float da = (l2x + s_l2ex[ka]) - 2.0f * acca;

        const float* eb = emb + (size_t)kb2 * DIM;
        float accb = 0.f;
#pragma unroll
        for (int d = 0; d < DIM; ++d) accb = __builtin_fmaf(x[d], eb[d], accb);
        const float db = (l2x + s_l2ex[kb2]) - 2.0f * accb;

        const int sel = (db < da) ? kb2 : ka;  // strict '<': lower index wins
        s_code[tid] = sel;
        codes_out[pix] = (float)sel;
    }
    __syncthreads();

    // ---- coalesced gather: 128 px * 16 float4 = 2048 float4, 8 iters ----
    const float4* emb4 = (const float4*)emb;
    float4* vout4 = (float4*)(vecs_out + (size_t)blockIdx.x * PPB * DIM);
#pragma unroll
    for (int it = 0; it < (PPB * DIM / 4) / BLK; ++it) {
        const int fidx = tid + it * BLK;
        const int pp = fidx >> 4, dd = fidx & 15;
        vout4[fidx] = emb4[(size_t)s_code[pp] * (DIM / 4) + dd];
    }
}

extern "C" void kernel_launch(void* const* d_in, const int* in_sizes, int n_in,
                              void* d_out, int out_size, void* d_ws,
                              size_t ws_size, hipStream_t stream) {
    const float* x_in = (const float*)d_in[0];  // [32,64,64,64] fp32
    const float* emb = (const float*)d_in[1];   // [512,64] fp32

    // workspace layout
    unsigned short* AH = (unsigned short*)d_ws;    // 64 KB (negated hi)
    unsigned short* ALO = AH + NUM_CODES * DIM;    // 64 KB (negated lo)
    float* l2e = (float*)(ALO + NUM_CODES * DIM);  // 2 KB
    float* l2eh = l2e + NUM_CODES;                 // 2 KB

    float* codes_out = (float*)d_out;        // NPIX floats (codes as f32)
    float* vecs_out = (float*)d_out + NPIX;  // NPIX*DIM floats

    hipLaunchKernelGGL(prep_kernel, dim3(32), dim3(256), 0, stream, emb, AH,
                       ALO, l2e, l2eh);
    hipLaunchKernelGGL(vq_main, dim3(NPIX / PPB), dim3(BLK), 0, stream, x_in,
                       AH, ALO, l2e, l2eh, emb, codes_out, vecs_out);
}

// Round 2
// 120.071 us; speedup vs baseline: 1.0511x; 1.0511x over previous
//
#include <hip/hip_runtime.h>

#define NUM_CODES 512
#define DIM 64
#define NPIX (32 * 64 * 64)  // 131072 pixels
#define CT (NUM_CODES / 16)  // 32 code tiles of 16 codes
#define BLK 256
#define NGRP 2               // pixel groups per wave (16 px each) -> 32 px/wave
#define PPB 128              // pixels per block = 4 waves * 32 px

typedef __attribute__((ext_vector_type(8))) short bf16x8;
typedef __attribute__((ext_vector_type(4))) float f32x4;

__device__ __forceinline__ unsigned short f2bf(float f) {
    unsigned u = __float_as_uint(f);
    return (unsigned short)((u + 0x7fffu + ((u >> 16) & 1u)) >> 16);
}
__device__ __forceinline__ float bf2f(unsigned short h) {
    return __uint_as_float(((unsigned)h) << 16);
}

// ---------------------------------------------------------------------------
// Prep: swizzle NEGATED codebook into bf16 hi/lo A-fragment order + exact
// l2e + l2e/2. A-frag (16x16x32): lane = (k_in_32/8)*16 + m, elem j = k%8.
// With -e in A and acc initialized to l2e/2, the MFMA output IS the
// selection key  l2e/2 - dot  directly.
// ---------------------------------------------------------------------------
__global__ __launch_bounds__(256) void prep_kernel(
    const float* __restrict__ emb, unsigned short* __restrict__ AH,
    unsigned short* __restrict__ ALO, float* __restrict__ l2e,
    float* __restrict__ l2eh) {
    const int t = blockIdx.x * 256 + threadIdx.x;  // 0..8191
    const int e0 = t * 4;
    const int c = e0 >> 6, d0 = e0 & 63;
    const float4 v = *(const float4*)(emb + c * DIM + d0);
    float f[4] = {-v.x, -v.y, -v.z, -v.w};  // NEGATED
    unsigned short h[4], l[4];
#pragma unroll
    for (int i = 0; i < 4; ++i) {
        h[i] = f2bf(f[i]);
        l[i] = f2bf(f[i] - bf2f(h[i]));
    }
    const int ct = c >> 4, mr = c & 15, s = d0 >> 5, q = (d0 & 31) >> 3,
              j0 = d0 & 7;
    const int base = ((ct * 2 + s) * 64 + (q * 16 + mr)) * 8 + j0;
    *(ushort4*)(AH + base) = make_ushort4(h[0], h[1], h[2], h[3]);
    *(ushort4*)(ALO + base) = make_ushort4(l[0], l[1], l[2], l[3]);

    if (t < NUM_CODES) {  // exact ||e||^2, validated pairwise-8 order
        const float* e = emb + t * DIM;
        float r[8];
#pragma unroll
        for (int j = 0; j < 8; ++j) {
            float w = e[j];
            r[j] = w * w;
        }
#pragma unroll
        for (int i = 8; i < DIM; i += 8)
#pragma unroll
            for (int j = 0; j < 8; ++j) {
                float w = e[i + j];
                r[j] += w * w;
            }
        float sv =
            ((r[0] + r[1]) + (r[2] + r[3])) + ((r[4] + r[5]) + (r[6] + r[7]));
        l2e[t] = sv;
        l2eh[t] = 0.5f * sv;
    }
}

// ---------------------------------------------------------------------------
// Main: 4 waves / 128 px. Changes vs R1 (theory: dependency-latency bound):
//  - each group's 6-MFMA chain split into two independent 3-chains
//    (accA init l2e/2, accB init 0, key = accA+accB) -> 4 chains/tile
//  - fragment prefetch 2 tiles deep (8 loads in flight), unroll 4
//  - s_setprio(1) around the MFMA cluster (barrier-free staggered waves)
//  - exact refine pair-parallel: 2 threads/pixel, lexicographic (d,k) min
// ---------------------------------------------------------------------------
__global__ __launch_bounds__(BLK, 4) void vq_main(
    const float* __restrict__ x_in, const unsigned short* __restrict__ AH,
    const unsigned short* __restrict__ ALO, const float* __restrict__ l2e,
    const float* __restrict__ l2eh, const float* __restrict__ emb,
    float* __restrict__ codes_out, float* __restrict__ vecs_out) {
    __shared__ float s_l2eh[NUM_CODES];
    __shared__ float s_l2ex[NUM_CODES];
    __shared__ int s_top[PPB][2];
    __shared__ int s_code[PPB];

    const int tid = threadIdx.x, lane = tid & 63, wave = tid >> 6;
    s_l2eh[tid] = l2eh[tid];
    s_l2eh[tid + 256] = l2eh[tid + 256];
    s_l2ex[tid] = l2e[tid];
    s_l2ex[tid + 256] = l2e[tid + 256];
    __syncthreads();

    const int p = lane & 15, q = lane >> 4;
    const int pw = blockIdx.x * PPB + wave * (16 * NGRP);  // wave's 32 px

    // ---- B fragments for NGRP groups: B[k][n]: n=lane&15, k=(lane>>4)*8+j --
    bf16x8 bh0[NGRP], bl0[NGRP], bh1[NGRP], bl1[NGRP];
#pragma unroll
    for (int g = 0; g < NGRP; ++g) {
        const float* xb = x_in + (size_t)(pw + g * 16 + p) * DIM + q * 8;
        float4 u0 = *(const float4*)(xb);
        float4 u1 = *(const float4*)(xb + 4);
        float4 u2 = *(const float4*)(xb + 32);
        float4 u3 = *(const float4*)(xb + 36);
        float f0[8] = {u0.x, u0.y, u0.z, u0.w, u1.x, u1.y, u1.z, u1.w};
        float f1[8] = {u2.x, u2.y, u2.z, u2.w, u3.x, u3.y, u3.z, u3.w};
#pragma unroll
        for (int j = 0; j < 8; ++j) {
            unsigned short hh = f2bf(f0[j]);
            bh0[g][j] = (short)hh;
            bl0[g][j] = (short)f2bf(f0[j] - bf2f(hh));
            unsigned short h2 = f2bf(f1[j]);
            bh1[g][j] = (short)h2;
            bl1[g][j] = (short)f2bf(f1[j] - bf2f(h2));
        }
    }

    const int rowbase = q * 4;  // C/D: row = (lane>>4)*4 + reg
    float d1[NGRP], d2[NGRP];
    int k1[NGRP], k2[NGRP];
#pragma unroll
    for (int g = 0; g < NGRP; ++g) {
        d1[g] = 3.4e38f;
        d2[g] = 3.4e38f;
        k1[g] = 0;
        k2[g] = 0;
    }

    const unsigned short* pAH = AH + lane * 8;
    const unsigned short* pAL = ALO + lane * 8;

    // ---- prime tiles 0 and 1 (2-deep prefetch pipeline) ----
    bf16x8 c0h = *(const bf16x8*)(pAH);
    bf16x8 c0l = *(const bf16x8*)(pAL);
    bf16x8 c1h = *(const bf16x8*)(pAH + 512);
    bf16x8 c1l = *(const bf16x8*)(pAL + 512);
    bf16x8 p0h = *(const bf16x8*)(pAH + 1024);
    bf16x8 p0l = *(const bf16x8*)(pAL + 1024);
    bf16x8 p1h = *(const bf16x8*)(pAH + 1024 + 512);
    bf16x8 p1l = *(const bf16x8*)(pAL + 1024 + 512);

#pragma unroll 4
    for (int ct = 0; ct < CT; ++ct) {
        // prefetch tile ct+2 (wraps; harmless redundant loads on last iters)
        const int nt = (ct + 2) & (CT - 1);
        const bf16x8 q0h = *(const bf16x8*)(pAH + nt * 1024);
        const bf16x8 q0l = *(const bf16x8*)(pAL + nt * 1024);
        const bf16x8 q1h = *(const bf16x8*)(pAH + nt * 1024 + 512);
        const bf16x8 q1l = *(const bf16x8*)(pAL + nt * 1024 + 512);

        const int kb = ct * 16 + rowbase;
        // acc-init with l2e/2: one ds_read_b128 (kb is 16B-aligned)
        const f32x4 acc_init = *(const f32x4*)&s_l2eh[kb];

        // ---- MFMA cluster: 4 independent 3-chains (2 groups x 2 halves) --
        f32x4 accA[NGRP], accB[NGRP];
        __builtin_amdgcn_s_setprio(1);
#pragma unroll
        for (int g = 0; g < NGRP; ++g) {
            f32x4 a = acc_init;
            a = __builtin_amdgcn_mfma_f32_16x16x32_bf16(c0h, bh0[g], a, 0, 0, 0);
            a = __builtin_amdgcn_mfma_f32_16x16x32_bf16(c0l, bh0[g], a, 0, 0, 0);
            a = __builtin_amdgcn_mfma_f32_16x16x32_bf16(c0h, bl0[g], a, 0, 0, 0);
            f32x4 b = {0.f, 0.f, 0.f, 0.f};
            b = __builtin_amdgcn_mfma_f32_16x16x32_bf16(c1h, bh1[g], b, 0, 0, 0);
            b = __builtin_amdgcn_mfma_f32_16x16x32_bf16(c1l, bh1[g], b, 0, 0, 0);
            b = __builtin_amdgcn_mfma_f32_16x16x32_bf16(c1h, bl1[g], b, 0, 0, 0);
            accA[g] = a;
            accB[g] = b;
        }
        __builtin_amdgcn_s_setprio(0);

        // ---- top-2 insert (validated med3 form; key = accA+accB) ----
#pragma unroll
        for (int g = 0; g < NGRP; ++g) {
#pragma unroll
            for (int r = 0; r < 4; ++r) {
                const float d = accA[g][r] + accB[g][r];  // l2e/2 - dot
                const int kk = kb + r;
                const bool c = d < d1[g], c2 = d < d2[g];
                const float nd2 = __builtin_amdgcn_fmed3f(d1[g], d2[g], d);
                const int nk2 = c2 ? kk : k2[g];
                k2[g] = c ? k1[g] : nk2;
                k1[g] = c ? kk : k1[g];
                d2[g] = nd2;
                d1[g] = fminf(d1[g], d);
            }
        }

        // rotate pipeline regs (renamed away under unroll)
        c0h = p0h; c0l = p0l; c1h = p1h; c1l = p1l;
        p0h = q0h; p0l = q0l; p1h = q1h; p1l = q1l;
    }

    // ---- cross-lane top-2 merge (lanes l, l^16, l^32 share pixel col) ----
#pragma unroll
    for (int g = 0; g < NGRP; ++g) {
        float a1 = d1[g], a2 = d2[g];
        int b1 = k1[g], b2 = k2[g];
#pragma unroll
        for (int off = 16; off <= 32; off <<= 1) {
            const float od1 = __shfl_xor(a1, off);
            const int ok1 = __shfl_xor(b1, off);
            const float od2 = __shfl_xor(a2, off);
            const int ok2 = __shfl_xor(b2, off);
            const bool c = od1 < a1;
            const float w1 = c ? od1 : a1;
            const int wk1 = c ? ok1 : b1;
            const float l1 = c ? a1 : od1;
            const int lk1 = c ? b1 : ok1;
            const bool cm = od2 < a2;
            const float m2 = cm ? od2 : a2;
            const int mk2 = cm ? ok2 : b2;
            const bool c3 = m2 < l1;
            a2 = c3 ? m2 : l1;
            b2 = c3 ? mk2 : lk1;
            a1 = w1;
            b1 = wk1;
        }
        if (lane < 16) {
            const int pb = wave * (16 * NGRP) + g * 16 + lane;
            s_top[pb][0] = b1;
            s_top[pb][1] = b2;
        }
    }
    __syncthreads();

    // ---- exact refine, pair-parallel: 2 threads per pixel, one candidate
    //      each; winner = lexicographic min of (d, k) — identical tie rule
    //      to the validated sequential version (strict '<', lower idx wins).
    {
        const int pixloc = tid >> 1, which = tid & 1;  // 256 thr = 2*PPB
        const int pix = blockIdx.x * PPB + pixloc;
        const int k_me = s_top[pixloc][which];
        const float* xr = x_in + (size_t)pix * DIM;
        float x[DIM];
#pragma unroll
        for (int jj = 0; jj < 16; ++jj) {
            const float4 v = *(const float4*)(xr + jj * 4);
            x[4 * jj + 0] = v.x;
            x[4 * jj + 1] = v.y;
            x[4 * jj + 2] = v.z;
            x[4 * jj + 3] = v.w;
        }
        float r[8];
#pragma unroll
        for (int j = 0; j < 8; ++j) r[j] = x[j] * x[j];
#pragma unroll
        for (int i = 8; i < DIM; i += 8)
#pragma unroll
            for (int j = 0; j < 8; ++j) r[j] += x[i + j] * x[i + j];
        const float l2x =
            ((r[0] + r[1]) + (r[2] + r[3])) + ((r[4] + r[5]) + (r[6] + r[7]));

        const float* em = emb + (size_t)k_me * DIM;
        float acc = 0.f;
#pragma unroll
        for (int d = 0; d < DIM; ++d) acc = __builtin_fmaf(x[d], em[d], acc);
        const float d_me = (l2x + s_l2ex[k_me]) - 2.0f * acc;

        const float d_o = __shfl_xor(d_me, 1);
        const int k_o = __shfl_xor(k_me, 1);
        const int sel =
            (d_me < d_o || (d_me == d_o && k_me < k_o)) ? k_me : k_o;
        if (which == 0) {
            s_code[pixloc] = sel;
            codes_out[pix] = (float)sel;
        }
    }
    __syncthreads();

    // ---- coalesced gather: 128 px * 16 float4 = 2048 float4, 8 iters ----
    const float4* emb4 = (const float4*)emb;
    float4* vout4 = (float4*)(vecs_out + (size_t)blockIdx.x * PPB * DIM);
#pragma unroll
    for (int it = 0; it < (PPB * DIM / 4) / BLK; ++it) {
        const int fidx = tid + it * BLK;
        const int pp = fidx >> 4, dd = fidx & 15;
        vout4[fidx] = emb4[(size_t)s_code[pp] * (DIM / 4) + dd];
    }
}

extern "C" void kernel_launch(void* const* d_in, const int* in_sizes, int n_in,
                              void* d_out, int out_size, void* d_ws,
                              size_t ws_size, hipStream_t stream) {
    const float* x_in = (const float*)d_in[0];  // [32,64,64,64] fp32
    const float* emb = (const float*)d_in[1];   // [512,64] fp32

    // workspace layout
    unsigned short* AH = (unsigned short*)d_ws;    // 64 KB (negated hi)
    unsigned short* ALO = AH + NUM_CODES * DIM;    // 64 KB (negated lo)
    float* l2e = (float*)(ALO + NUM_CODES * DIM);  // 2 KB
    float* l2eh = l2e + NUM_CODES;                 // 2 KB

    float* codes_out = (float*)d_out;        // NPIX floats (codes as f32)
    float* vecs_out = (float*)d_out + NPIX;  // NPIX*DIM floats

    hipLaunchKernelGGL(prep_kernel, dim3(32), dim3(256), 0, stream, emb, AH,
                       ALO, l2e, l2eh);
    hipLaunchKernelGGL(vq_main, dim3(NPIX / PPB), dim3(BLK), 0, stream, x_in,
                       AH, ALO, l2e, l2eh, emb, codes_out, vecs_out);
}